// Round 3
// baseline (265.257 us; speedup 1.0000x reference)
//
#include <hip/hip_runtime.h>
#include <hip/hip_bf16.h>

#define B_ROWS 8192
#define FEAT   256
#define NCH    4          // j-range chunks -> grid = 4 x 64 = 256 blocks
#define CH_COLS 2048
#define NJT    16         // 128-col j-tiles per chunk

typedef float f32x4 __attribute__((ext_vector_type(4)));
typedef _Float16 f16x8 __attribute__((ext_vector_type(8)));

// ---------------- kernel 1: row ssq, global sum/ssq (f64), fp16 convert ----
__global__ __launch_bounds__(256) void prep_kernel(
    const float* __restrict__ x, unsigned short* __restrict__ xh,
    float* __restrict__ sq, double* __restrict__ gacc)
{
  int tid = threadIdx.x;
  int l = tid & 63, wid = tid >> 6;
  int row = blockIdx.x * 4 + wid;
  const float4* xv = (const float4*)(x + (size_t)row * FEAT);
  float4 v = xv[l];
  ushort4 u;
  u.x = __builtin_bit_cast(unsigned short, (_Float16)v.x);
  u.y = __builtin_bit_cast(unsigned short, (_Float16)v.y);
  u.z = __builtin_bit_cast(unsigned short, (_Float16)v.z);
  u.w = __builtin_bit_cast(unsigned short, (_Float16)v.w);
  ((ushort4*)(xh + (size_t)row * FEAT))[l] = u;
  float ssq  = v.x*v.x + v.y*v.y + v.z*v.z + v.w*v.w;
  float ssum = v.x + v.y + v.z + v.w;
  #pragma unroll
  for (int m = 32; m; m >>= 1) {
    ssq  += __shfl_xor(ssq, m);
    ssum += __shfl_xor(ssum, m);
  }
  if (l == 0) sq[row] = ssq;
  __shared__ float red[8];
  if (l == 0) { red[wid*2] = ssum; red[wid*2+1] = ssq; }
  __syncthreads();
  if (tid == 0) {
    float s = red[0]+red[2]+red[4]+red[6];
    float q = red[1]+red[3]+red[5]+red[7];
    atomicAdd(&gacc[0], (double)s);
    atomicAdd(&gacc[1], (double)q);
  }
}

// ---------------- epilogue: d2 -> dist -> exp2, accumulate den/num ---------
template<bool DIAG>
__device__ __forceinline__ void epilogue(
    const f32x4 (&acc)[4][4], const float* __restrict__ sq,
    const int* __restrict__ y, int j0, int wc, int l15,
    int i0q, const float (&sqi)[16], const int (&yiv)[16],
    float (&sden)[16], float (&snum)[16], float nscale2)
{
  int jb = j0 + wc*64 + l15;
  float sqj[4]; int yj[4];
  #pragma unroll
  for (int cb = 0; cb < 4; ++cb) {
    int j = jb + cb*16;
    sqj[cb] = sq[j];
    yj[cb]  = y[j];           // y is int32 per harness convention
  }
  #pragma unroll
  for (int rb = 0; rb < 4; ++rb) {
    #pragma unroll
    for (int r = 0; r < 4; ++r) {
      float si = sqi[rb*4+r];
      int   ig = i0q + rb*16 + r;
      int   yi = yiv[rb*4+r];
      float dacc = 0.f, nacc = 0.f;
      #pragma unroll
      for (int cb = 0; cb < 4; ++cb) {
        float S  = acc[rb][cb][r];
        float d2 = fmaf(S, -2.0f, si + sqj[cb]);
        d2 = fmaxf(d2, 0.0f);
        float e  = __builtin_amdgcn_exp2f(__builtin_amdgcn_sqrtf(d2) * nscale2);
        bool offd = !DIAG || (ig != jb + cb*16);
        dacc += offd ? e : 0.0f;
        nacc += (yi == yj[cb] && offd) ? e : 0.0f;
      }
      sden[rb*4+r] += dacc;
      snum[rb*4+r] += nacc;
    }
  }
}

// ---------------- kernel 2: fused GEMM + online logsumexp -----------------
// block 256 (4 waves), block tile 128x128, wave tile 64x64 (4x4 MFMA blocks)
// LDS: A tile 64KB @0, B tile 64KB @65536, granule-XOR swizzled.
__global__ __launch_bounds__(256, 1) void snn_main(
    const unsigned short* __restrict__ xh, const float* __restrict__ sq,
    const int* __restrict__ y, const float* __restrict__ T,
    const double* __restrict__ gacc,
    float* __restrict__ pden, float* __restrict__ pnum)
{
  extern __shared__ char smem[];
  int tid = threadIdx.x;
  int l = tid & 63, wid = tid >> 6;
  int wr = wid >> 1, wc = wid & 1;
  int quad = l >> 4, l15 = l & 15;
  int ch = blockIdx.x, it = blockIdx.y;
  int i0 = it * 128, chbase = ch * CH_COLS;

  // uniform scale: -10^T / std * log2(e)
  double ssum = gacc[0], sssq = gacc[1];
  const double n = (double)B_ROWS * FEAT;
  double var = (sssq - ssum * ssum / n) / (n - 1.0);
  float stdv = (float)sqrt(var);
  float p10  = __builtin_amdgcn_exp2f(T[0] * 3.3219280948873623f);
  float nscale2 = -(p10 * 1.4426950408889634f / stdv);

  int dj = -1;
  if (i0 >= chbase && i0 < chbase + CH_COLS) dj = (i0 - chbase) >> 7;

  // per-lane row stats (rows i0q + rb*16 + r, duplicated over 16 lanes/quad)
  float sqi[16]; int yiv[16];
  int i0q = i0 + wr*64 + quad*4;
  #pragma unroll
  for (int rb = 0; rb < 4; ++rb)
    #pragma unroll
    for (int r = 0; r < 4; ++r) {
      int idx = i0q + rb*16 + r;
      sqi[rb*4+r] = sq[idx];
      yiv[rb*4+r] = y[idx];
    }

  const char* xbc = (const char*)xh;
  // stage A tile once (rows i0..i0+128), swizzle: granule g -> g ^ (row&7)
  {
    const uint4* gA = (const uint4*)(xbc + (size_t)i0 * 512);
    uint4 tmp[16];
    #pragma unroll
    for (int s = 0; s < 16; ++s) tmp[s] = gA[tid + 256*s];
    #pragma unroll
    for (int s = 0; s < 16; ++s) {
      int ll = tid + 256*s;
      int rw = ll >> 5, g = ll & 31;
      *(uint4*)(smem + rw*512 + ((g ^ (rw & 7)) << 4)) = tmp[s];
    }
  }

  float sden[16], snum[16];
  #pragma unroll
  for (int v = 0; v < 16; ++v) { sden[v] = 0.f; snum[v] = 0.f; }
  f32x4 acc[4][4];
  const f32x4 zero4 = {0.f, 0.f, 0.f, 0.f};

  for (int jt = 0; jt < NJT; ++jt) {
    int j0 = chbase + jt * 128;
    // issue B-tile loads early (hidden behind previous tile's epilogue)
    uint4 breg[16];
    const uint4* gB = (const uint4*)(xbc + (size_t)j0 * 512);
    #pragma unroll
    for (int s = 0; s < 16; ++s) breg[s] = gB[tid + 256*s];

    if (jt > 0) {
      int pj0 = j0 - 128;
      if (jt - 1 == dj)
        epilogue<true >(acc, sq, y, pj0, wc, l15, i0q, sqi, yiv, sden, snum, nscale2);
      else
        epilogue<false>(acc, sq, y, pj0, wc, l15, i0q, sqi, yiv, sden, snum, nscale2);
    }
    #pragma unroll
    for (int rb = 0; rb < 4; ++rb)
      #pragma unroll
      for (int cb = 0; cb < 4; ++cb)
        acc[rb][cb] = zero4;

    __syncthreads();   // all waves done reading previous B tile
    #pragma unroll
    for (int s = 0; s < 16; ++s) {
      int ll = tid + 256*s;
      int rw = ll >> 5, g = ll & 31;
      *(uint4*)(smem + 65536 + rw*512 + ((g ^ (rw & 7)) << 4)) = breg[s];
    }
    __syncthreads();   // B tile visible

    #pragma unroll
    for (int kk = 0; kk < 8; ++kk) {
      f16x8 av[4], bv[4];
      #pragma unroll
      for (int rb = 0; rb < 4; ++rb) {
        int rw = wr*64 + rb*16 + l15;
        av[rb] = *(const f16x8*)(smem + rw*512 + ((((kk<<2)|quad) ^ (l15 & 7)) << 4));
      }
      #pragma unroll
      for (int cb = 0; cb < 4; ++cb) {
        int rw = wc*64 + cb*16 + l15;
        bv[cb] = *(const f16x8*)(smem + 65536 + rw*512 + ((((kk<<2)|quad) ^ (l15 & 7)) << 4));
      }
      #pragma unroll
      for (int rb = 0; rb < 4; ++rb)
        #pragma unroll
        for (int cb = 0; cb < 4; ++cb)
          acc[rb][cb] = __builtin_amdgcn_mfma_f32_16x16x32_f16(av[rb], bv[cb], acc[rb][cb], 0, 0, 0);
    }
  }
  {
    int pj0 = chbase + (NJT-1) * 128;
    if (NJT-1 == dj)
      epilogue<true >(acc, sq, y, pj0, wc, l15, i0q, sqi, yiv, sden, snum, nscale2);
    else
      epilogue<false>(acc, sq, y, pj0, wc, l15, i0q, sqi, yiv, sden, snum, nscale2);
  }

  // reduce across the 16 lanes of each quad (columns of the wave tile)
  #pragma unroll
  for (int v = 0; v < 16; ++v) {
    #pragma unroll
    for (int m = 1; m <= 8; m <<= 1) {
      sden[v] += __shfl_xor(sden[v], m);
      snum[v] += __shfl_xor(snum[v], m);
    }
  }
  if (l15 == 0) {
    int base = ((it*NCH + ch)*2 + wc) * 128;
    #pragma unroll
    for (int rb = 0; rb < 4; ++rb)
      #pragma unroll
      for (int r = 0; r < 4; ++r) {
        int rin = wr*64 + rb*16 + quad*4 + r;
        pden[base + rin] = sden[rb*4+r];
        pnum[base + rin] = snum[rb*4+r];
      }
  }
}

// ---------------- kernel 3: combine partials, final loss -------------------
__global__ __launch_bounds__(256) void final_kernel(
    const float* __restrict__ pden, const float* __restrict__ pnum,
    float* __restrict__ out)
{
  int tid = threadIdx.x;
  float tot = 0.f;
  for (int k = 0; k < 32; ++k) {
    int row = tid + 256*k;
    int itt = row >> 7, rin = row & 127;
    float den = 0.f, num = 0.f;
    #pragma unroll
    for (int p = 0; p < 8; ++p) {
      den += pden[(itt*8 + p)*128 + rin];
      num += pnum[(itt*8 + p)*128 + rin];
    }
    if (num > 0.f)
      tot += 0.6931471805599453f *
             (__builtin_amdgcn_logf(num) - __builtin_amdgcn_logf(den));
  }
  #pragma unroll
  for (int m = 32; m; m >>= 1) tot += __shfl_xor(tot, m);
  __shared__ float red[4];
  if ((tid & 63) == 0) red[tid >> 6] = tot;
  __syncthreads();
  if (tid == 0) out[0] = -(red[0]+red[1]+red[2]+red[3]) / 8192.0f;
}

extern "C" void kernel_launch(void* const* d_in, const int* in_sizes, int n_in,
                              void* d_out, int out_size, void* d_ws, size_t ws_size,
                              hipStream_t stream)
{
  (void)in_sizes; (void)n_in; (void)out_size; (void)ws_size;
  const float* x  = (const float*)d_in[0];
  const int* y    = (const int*)d_in[1];   // int64 in reference -> int32 here
  const float* T  = (const float*)d_in[2];
  char* ws = (char*)d_ws;
  double* gacc = (double*)ws;                            // 16 B
  float* sq    = (float*)(ws + 256);                     // 32 KB
  unsigned short* xh = (unsigned short*)(ws + 65536);    // 4 MB fp16
  float* pden  = (float*)(ws + 65536 + 4194304);         // 64*8*128 f32
  float* pnum  = pden + 64*8*128;

  hipMemsetAsync(ws, 0, 256, stream);
  hipLaunchKernelGGL(prep_kernel, dim3(B_ROWS/4), dim3(256), 0, stream,
                     x, xh, sq, gacc);
  hipFuncSetAttribute((const void*)snn_main,
                      hipFuncAttributeMaxDynamicSharedMemorySize, 131072);
  hipLaunchKernelGGL(snn_main, dim3(NCH, B_ROWS/128), dim3(256), 131072, stream,
                     xh, sq, y, T, gacc, pden, pnum);
  hipLaunchKernelGGL(final_kernel, dim3(1), dim3(256), 0, stream,
                     pden, pnum, (float*)d_out);
}

// Round 6
// 190.483 us; speedup vs baseline: 1.3926x; 1.3926x over previous
//
#include <hip/hip_runtime.h>

#define B_ROWS 8192
#define FEAT   256
#define NCH    4          // j-range chunks -> grid = 4 x 64 = 256 blocks
#define CH_COLS 2048
#define NJT    16         // 128-col j-tiles per chunk

typedef float f32x4 __attribute__((ext_vector_type(4)));
typedef _Float16 f16x8 __attribute__((ext_vector_type(8)));

typedef const __attribute__((address_space(1))) unsigned int* gas_ptr;
typedef __attribute__((address_space(3))) unsigned int* las_ptr;

__device__ __forceinline__ void gload_lds16(const void* g, void* l) {
  // HW semantics: LDS dest = wave-uniform base + lane*16 (m104/m108)
  __builtin_amdgcn_global_load_lds((gas_ptr)g, (las_ptr)l, 16, 0, 0);
}

// ---------------- kernel 1: row ssq, global sum/ssq (f64), fp16 convert ----
__global__ __launch_bounds__(256) void prep_kernel(
    const float* __restrict__ x, unsigned short* __restrict__ xh,
    float* __restrict__ sq, double* __restrict__ gacc)
{
  int tid = threadIdx.x;
  int l = tid & 63, wid = tid >> 6;
  int row = blockIdx.x * 4 + wid;
  const float4* xv = (const float4*)(x + (size_t)row * FEAT);
  float4 v = xv[l];
  ushort4 u;
  u.x = __builtin_bit_cast(unsigned short, (_Float16)v.x);
  u.y = __builtin_bit_cast(unsigned short, (_Float16)v.y);
  u.z = __builtin_bit_cast(unsigned short, (_Float16)v.z);
  u.w = __builtin_bit_cast(unsigned short, (_Float16)v.w);
  ((ushort4*)(xh + (size_t)row * FEAT))[l] = u;
  float ssq  = v.x*v.x + v.y*v.y + v.z*v.z + v.w*v.w;
  float ssum = v.x + v.y + v.z + v.w;
  #pragma unroll
  for (int m = 32; m; m >>= 1) {
    ssq  += __shfl_xor(ssq, m);
    ssum += __shfl_xor(ssum, m);
  }
  if (l == 0) sq[row] = ssq;
  __shared__ float red[8];
  if (l == 0) { red[wid*2] = ssum; red[wid*2+1] = ssq; }
  __syncthreads();
  if (tid == 0) {
    float s = red[0]+red[2]+red[4]+red[6];
    float q = red[1]+red[3]+red[5]+red[7];
    atomicAdd(&gacc[0], (double)s);
    atomicAdd(&gacc[1], (double)q);
  }
}

// ---------------- epilogue: d2 -> dist -> exp2, accumulate den/num ---------
template<bool DIAG>
__device__ __forceinline__ void epilogue(
    const f32x4 (&acc)[4][4], const float* __restrict__ sq,
    const int* __restrict__ y, int j0, int wc, int l15,
    int i0q, const float (&sqi)[16], const int (&yiv)[16],
    float (&sden)[16], float (&snum)[16], float nscale2)
{
  int jb = j0 + wc*64 + l15;
  float sqj[4]; int yj[4];
  #pragma unroll
  for (int cb = 0; cb < 4; ++cb) {
    int j = jb + cb*16;
    sqj[cb] = sq[j];
    yj[cb]  = y[j];
  }
  #pragma unroll
  for (int rb = 0; rb < 4; ++rb) {
    #pragma unroll
    for (int r = 0; r < 4; ++r) {
      float si = sqi[rb*4+r];
      int   ig = i0q + rb*16 + r;
      int   yi = yiv[rb*4+r];
      float dacc = 0.f, nacc = 0.f;
      #pragma unroll
      for (int cb = 0; cb < 4; ++cb) {
        float S  = acc[rb][cb][r];
        float d2 = fmaf(S, -2.0f, si + sqj[cb]);
        d2 = fmaxf(d2, 0.0f);
        float e  = __builtin_amdgcn_exp2f(__builtin_amdgcn_sqrtf(d2) * nscale2);
        bool offd = !DIAG || (ig != jb + cb*16);
        dacc += offd ? e : 0.0f;
        nacc += (yi == yj[cb] && offd) ? e : 0.0f;
      }
      sden[rb*4+r] += dacc;
      snum[rb*4+r] += nacc;
    }
  }
}

// ---------------- kernel 2: fused GEMM + online accumulation --------------
// R3 structure verbatim; staging replaced by swizzle-preserving
// global_load_lds (per-lane global granule g = s31 ^ (rw&7) reproduces the
// exact LDS image of R3's ds_write path -> frag reads unchanged).
__global__ __launch_bounds__(256, 1) void snn_main(
    const unsigned short* __restrict__ xh, const float* __restrict__ sq,
    const int* __restrict__ y, const float* __restrict__ T,
    const double* __restrict__ gacc,
    float* __restrict__ pden, float* __restrict__ pnum)
{
  extern __shared__ char smem[];
  char* lA = smem;
  char* lB = smem + 65536;
  int tid = threadIdx.x;
  int l = tid & 63, wid = tid >> 6;
  int wr = wid >> 1, wc = wid & 1;
  int quad = l >> 4, l15 = l & 15;
  int l5 = l >> 5, s31 = l & 31;
  int ch = blockIdx.x, it = blockIdx.y;
  int i0 = it * 128, chbase = ch * CH_COLS;

  const char* xbc = (const char*)xh;

  // stage A tile async (rows i0..i0+128): chunk c = 2 rows = 1024 B
  {
    const char* gA = xbc + (size_t)i0 * 512;
    #pragma unroll
    for (int s = 0; s < 16; ++s) {
      int c  = wid*16 + s;
      int rw = 2*c + l5;
      int gg = s31 ^ (rw & 7);
      gload_lds16(gA + rw*512 + gg*16, lA + c*1024);
    }
  }

  // uniform scale: -10^T / std * log2(e)
  double ssum = gacc[0], sssq = gacc[1];
  const double n = (double)B_ROWS * FEAT;
  double var = (sssq - ssum * ssum / n) / (n - 1.0);
  float stdv = (float)sqrt(var);
  float p10  = __builtin_amdgcn_exp2f(T[0] * 3.3219280948873623f);
  float nscale2 = -(p10 * 1.4426950408889634f / stdv);

  int dj = -1;
  if (i0 >= chbase && i0 < chbase + CH_COLS) dj = (i0 - chbase) >> 7;

  // per-lane row stats
  float sqi[16]; int yiv[16];
  int i0q = i0 + wr*64 + quad*4;
  #pragma unroll
  for (int rb = 0; rb < 4; ++rb)
    #pragma unroll
    for (int r = 0; r < 4; ++r) {
      int idx = i0q + rb*16 + r;
      sqi[rb*4+r] = sq[idx];
      yiv[rb*4+r] = y[idx];
    }

  float sden[16], snum[16];
  #pragma unroll
  for (int v = 0; v < 16; ++v) { sden[v] = 0.f; snum[v] = 0.f; }
  f32x4 acc[4][4];
  const f32x4 zero4 = {0.f, 0.f, 0.f, 0.f};

  for (int jt = 0; jt < NJT; ++jt) {
    int j0 = chbase + jt * 128;

    __syncthreads();   // all waves done reading lB of previous tile
    // issue next B tile direct-to-LDS (latency hidden by epilogue below)
    {
      const char* gB = xbc + (size_t)j0 * 512;
      #pragma unroll
      for (int s = 0; s < 16; ++s) {
        int c  = wid*16 + s;
        int rw = 2*c + l5;
        int gg = s31 ^ (rw & 7);
        gload_lds16(gB + rw*512 + gg*16, lB + c*1024);
      }
    }

    if (jt > 0) {
      int pj0 = j0 - 128;
      if (jt - 1 == dj)
        epilogue<true >(acc, sq, y, pj0, wc, l15, i0q, sqi, yiv, sden, snum, nscale2);
      else
        epilogue<false>(acc, sq, y, pj0, wc, l15, i0q, sqi, yiv, sden, snum, nscale2);
    }
    #pragma unroll
    for (int rb = 0; rb < 4; ++rb)
      #pragma unroll
      for (int cb = 0; cb < 4; ++cb)
        acc[rb][cb] = zero4;

    __syncthreads();   // drains vmcnt: A (first iter) and B tiles visible

    #pragma unroll
    for (int kk = 0; kk < 8; ++kk) {
      f16x8 av[4], bv[4];
      #pragma unroll
      for (int rb = 0; rb < 4; ++rb) {
        int rw = wr*64 + rb*16 + l15;
        av[rb] = *(const f16x8*)(lA + rw*512 + ((((kk<<2)|quad) ^ (l15 & 7)) << 4));
      }
      #pragma unroll
      for (int cb = 0; cb < 4; ++cb) {
        int rw = wc*64 + cb*16 + l15;
        bv[cb] = *(const f16x8*)(lB + rw*512 + ((((kk<<2)|quad) ^ (l15 & 7)) << 4));
      }
      #pragma unroll
      for (int rb = 0; rb < 4; ++rb)
        #pragma unroll
        for (int cb = 0; cb < 4; ++cb)
          acc[rb][cb] = __builtin_amdgcn_mfma_f32_16x16x32_f16(av[rb], bv[cb], acc[rb][cb], 0, 0, 0);
    }
  }
  {
    int pj0 = chbase + (NJT-1) * 128;
    if (NJT-1 == dj)
      epilogue<true >(acc, sq, y, pj0, wc, l15, i0q, sqi, yiv, sden, snum, nscale2);
    else
      epilogue<false>(acc, sq, y, pj0, wc, l15, i0q, sqi, yiv, sden, snum, nscale2);
  }

  // reduce across the 16 lanes of each quad (columns of the wave tile)
  #pragma unroll
  for (int v = 0; v < 16; ++v) {
    #pragma unroll
    for (int m = 1; m <= 8; m <<= 1) {
      sden[v] += __shfl_xor(sden[v], m);
      snum[v] += __shfl_xor(snum[v], m);
    }
  }
  if (l15 == 0) {
    int base = ((it*NCH + ch)*2 + wc) * 128;
    #pragma unroll
    for (int rb = 0; rb < 4; ++rb)
      #pragma unroll
      for (int r = 0; r < 4; ++r) {
        int rin = wr*64 + rb*16 + quad*4 + r;
        pden[base + rin] = sden[rb*4+r];
        pnum[base + rin] = snum[rb*4+r];
      }
  }
}

// ---------------- kernel 3: combine partials, final loss -------------------
__global__ __launch_bounds__(256) void final_kernel(
    const float* __restrict__ pden, const float* __restrict__ pnum,
    float* __restrict__ out)
{
  int tid = threadIdx.x;
  float tot = 0.f;
  for (int k = 0; k < 32; ++k) {
    int row = tid + 256*k;
    int itt = row >> 7, rin = row & 127;
    float den = 0.f, num = 0.f;
    #pragma unroll
    for (int p = 0; p < 8; ++p) {
      den += pden[(itt*8 + p)*128 + rin];
      num += pnum[(itt*8 + p)*128 + rin];
    }
    if (num > 0.f)
      tot += 0.6931471805599453f *
             (__builtin_amdgcn_logf(num) - __builtin_amdgcn_logf(den));
  }
  #pragma unroll
  for (int m = 32; m; m >>= 1) tot += __shfl_xor(tot, m);
  __shared__ float red[4];
  if ((tid & 63) == 0) red[tid >> 6] = tot;
  __syncthreads();
  if (tid == 0) out[0] = -(red[0]+red[1]+red[2]+red[3]) / 8192.0f;
}

extern "C" void kernel_launch(void* const* d_in, const int* in_sizes, int n_in,
                              void* d_out, int out_size, void* d_ws, size_t ws_size,
                              hipStream_t stream)
{
  (void)in_sizes; (void)n_in; (void)out_size; (void)ws_size;
  const float* x  = (const float*)d_in[0];
  const int* y    = (const int*)d_in[1];   // int64 in reference -> int32 here
  const float* T  = (const float*)d_in[2];
  char* ws = (char*)d_ws;
  double* gacc = (double*)ws;                            // 16 B
  float* sq    = (float*)(ws + 256);                     // 32 KB
  unsigned short* xh = (unsigned short*)(ws + 65536);    // 4 MB fp16
  float* pden  = (float*)(ws + 65536 + 4194304);         // 64*8*128 f32
  float* pnum  = pden + 64*8*128;

  hipMemsetAsync(ws, 0, 256, stream);
  hipLaunchKernelGGL(prep_kernel, dim3(B_ROWS/4), dim3(256), 0, stream,
                     x, xh, sq, gacc);
  hipFuncSetAttribute((const void*)snn_main,
                      hipFuncAttributeMaxDynamicSharedMemorySize, 131072);
  hipLaunchKernelGGL(snn_main, dim3(NCH, B_ROWS/128), dim3(256), 131072, stream,
                     xh, sq, y, T, gacc, pden, pnum);
  hipLaunchKernelGGL(final_kernel, dim3(1), dim3(256), 0, stream,
                     pden, pnum, (float*)d_out);
}

// Round 8
// 143.215 us; speedup vs baseline: 1.8522x; 1.3300x over previous
//
#include <hip/hip_runtime.h>

#define B_ROWS 8192
#define FEAT   256
#define NCH    4          // j-range chunks -> grid = 4 x 64 = 256 blocks
#define CH_COLS 2048
#define NJT    16         // 128-col j-tiles per chunk

typedef float f32x4 __attribute__((ext_vector_type(4)));
typedef _Float16 f16x8 __attribute__((ext_vector_type(8)));

typedef const __attribute__((address_space(1))) unsigned int* gas_ptr;
typedef __attribute__((address_space(3))) unsigned int* las_ptr;

__device__ __forceinline__ void gload_lds16(const void* g, void* l) {
  // HW semantics: LDS dest = wave-uniform base + lane*16
  __builtin_amdgcn_global_load_lds((gas_ptr)g, (las_ptr)l, 16, 0, 0);
}

// ---- kernel 1: fp16 convert, row ssq, per-block f32 partials (no atomics)
__global__ __launch_bounds__(256) void prep_kernel(
    const float* __restrict__ x, unsigned short* __restrict__ xh,
    float* __restrict__ sq, float* __restrict__ part_s,
    float* __restrict__ part_q)
{
  int tid = threadIdx.x;
  int l = tid & 63, wid = tid >> 6;
  int row = blockIdx.x * 4 + wid;
  const float4* xv = (const float4*)(x + (size_t)row * FEAT);
  float4 v = xv[l];
  ushort4 u;
  u.x = __builtin_bit_cast(unsigned short, (_Float16)v.x);
  u.y = __builtin_bit_cast(unsigned short, (_Float16)v.y);
  u.z = __builtin_bit_cast(unsigned short, (_Float16)v.z);
  u.w = __builtin_bit_cast(unsigned short, (_Float16)v.w);
  ((ushort4*)(xh + (size_t)row * FEAT))[l] = u;
  float ssq  = v.x*v.x + v.y*v.y + v.z*v.z + v.w*v.w;
  float ssum = v.x + v.y + v.z + v.w;
  #pragma unroll
  for (int m = 32; m; m >>= 1) {
    ssq  += __shfl_xor(ssq, m);
    ssum += __shfl_xor(ssum, m);
  }
  if (l == 0) sq[row] = ssq;
  __shared__ float red[8];
  if (l == 0) { red[wid*2] = ssum; red[wid*2+1] = ssq; }
  __syncthreads();
  if (tid == 0) {
    part_s[blockIdx.x] = red[0]+red[2]+red[4]+red[6];
    part_q[blockIdx.x] = red[1]+red[3]+red[5]+red[7];
  }
}

// ---- kernel 1b: reduce 2048 partials -> gacc (f64, one block)
__global__ __launch_bounds__(256) void reduce_kernel(
    const float* __restrict__ part_s, const float* __restrict__ part_q,
    double* __restrict__ gacc)
{
  int tid = threadIdx.x;
  double s = 0.0, q = 0.0;
  #pragma unroll
  for (int k = 0; k < 8; ++k) {
    s += (double)part_s[tid + 256*k];
    q += (double)part_q[tid + 256*k];
  }
  #pragma unroll
  for (int m = 32; m; m >>= 1) {
    s += __shfl_xor(s, m);
    q += __shfl_xor(q, m);
  }
  __shared__ double rs[4], rq[4];
  if ((tid & 63) == 0) { rs[tid >> 6] = s; rq[tid >> 6] = q; }
  __syncthreads();
  if (tid == 0) {
    gacc[0] = rs[0]+rs[1]+rs[2]+rs[3];
    gacc[1] = rq[0]+rq[1]+rq[2]+rq[3];
  }
}

// ---- epilogue: d2 -> dist -> exp2, accumulate den/num (R6, proven) -------
template<bool DIAG>
__device__ __forceinline__ void epilogue(
    const f32x4 (&acc)[4][4], const float* __restrict__ sq,
    const int* __restrict__ y, int j0, int wc, int l15,
    int i0q, const float (&sqi)[16], const int (&yiv)[16],
    float (&sden)[16], float (&snum)[16], float nscale2)
{
  int jb = j0 + wc*64 + l15;
  float sqj[4]; int yj[4];
  #pragma unroll
  for (int cb = 0; cb < 4; ++cb) {
    int j = jb + cb*16;
    sqj[cb] = sq[j];
    yj[cb]  = y[j];
  }
  #pragma unroll
  for (int rb = 0; rb < 4; ++rb) {
    #pragma unroll
    for (int r = 0; r < 4; ++r) {
      float si = sqi[rb*4+r];
      int   ig = i0q + rb*16 + r;
      int   yi = yiv[rb*4+r];
      float dacc = 0.f, nacc = 0.f;
      #pragma unroll
      for (int cb = 0; cb < 4; ++cb) {
        float S  = acc[rb][cb][r];
        float d2 = fmaf(S, -2.0f, si + sqj[cb]);
        d2 = fmaxf(d2, 0.0f);
        float e  = __builtin_amdgcn_exp2f(__builtin_amdgcn_sqrtf(d2) * nscale2);
        bool offd = !DIAG || (ig != jb + cb*16);
        dacc += offd ? e : 0.0f;
        nacc += (yi == yj[cb] && offd) ? e : 0.0f;
      }
      sden[rb*4+r] += dacc;
      snum[rb*4+r] += nacc;
    }
  }
}

// ---- kernel 2: fused GEMM + accumulation (byte-identical to R6) ----------
__global__ __launch_bounds__(256, 1) void snn_main(
    const unsigned short* __restrict__ xh, const float* __restrict__ sq,
    const int* __restrict__ y, const float* __restrict__ T,
    const double* __restrict__ gacc,
    float* __restrict__ pden, float* __restrict__ pnum)
{
  extern __shared__ char smem[];
  char* lA = smem;
  char* lB = smem + 65536;
  int tid = threadIdx.x;
  int l = tid & 63, wid = tid >> 6;
  int wr = wid >> 1, wc = wid & 1;
  int quad = l >> 4, l15 = l & 15;
  int l5 = l >> 5, s31 = l & 31;
  int ch = blockIdx.x, it = blockIdx.y;
  int i0 = it * 128, chbase = ch * CH_COLS;

  const char* xbc = (const char*)xh;

  // stage A tile async (rows i0..i0+128): chunk c = 2 rows = 1024 B
  {
    const char* gA = xbc + (size_t)i0 * 512;
    #pragma unroll
    for (int s = 0; s < 16; ++s) {
      int c  = wid*16 + s;
      int rw = 2*c + l5;
      int gg = s31 ^ (rw & 7);
      gload_lds16(gA + rw*512 + gg*16, lA + c*1024);
    }
  }

  // uniform scale: -10^T / std * log2(e)
  double ssum = gacc[0], sssq = gacc[1];
  const double n = (double)B_ROWS * FEAT;
  double var = (sssq - ssum * ssum / n) / (n - 1.0);
  float stdv = (float)sqrt(var);
  float p10  = __builtin_amdgcn_exp2f(T[0] * 3.3219280948873623f);
  float nscale2 = -(p10 * 1.4426950408889634f / stdv);

  int dj = -1;
  if (i0 >= chbase && i0 < chbase + CH_COLS) dj = (i0 - chbase) >> 7;

  // per-lane row stats
  float sqi[16]; int yiv[16];
  int i0q = i0 + wr*64 + quad*4;
  #pragma unroll
  for (int rb = 0; rb < 4; ++rb)
    #pragma unroll
    for (int r = 0; r < 4; ++r) {
      int idx = i0q + rb*16 + r;
      sqi[rb*4+r] = sq[idx];
      yiv[rb*4+r] = y[idx];
    }

  float sden[16], snum[16];
  #pragma unroll
  for (int v = 0; v < 16; ++v) { sden[v] = 0.f; snum[v] = 0.f; }
  f32x4 acc[4][4];
  const f32x4 zero4 = {0.f, 0.f, 0.f, 0.f};

  for (int jt = 0; jt < NJT; ++jt) {
    int j0 = chbase + jt * 128;

    __syncthreads();   // all waves done reading lB of previous tile
    // issue next B tile direct-to-LDS (latency hidden by epilogue below)
    {
      const char* gB = xbc + (size_t)j0 * 512;
      #pragma unroll
      for (int s = 0; s < 16; ++s) {
        int c  = wid*16 + s;
        int rw = 2*c + l5;
        int gg = s31 ^ (rw & 7);
        gload_lds16(gB + rw*512 + gg*16, lB + c*1024);
      }
    }

    if (jt > 0) {
      int pj0 = j0 - 128;
      if (jt - 1 == dj)
        epilogue<true >(acc, sq, y, pj0, wc, l15, i0q, sqi, yiv, sden, snum, nscale2);
      else
        epilogue<false>(acc, sq, y, pj0, wc, l15, i0q, sqi, yiv, sden, snum, nscale2);
    }
    #pragma unroll
    for (int rb = 0; rb < 4; ++rb)
      #pragma unroll
      for (int cb = 0; cb < 4; ++cb)
        acc[rb][cb] = zero4;

    __syncthreads();   // drains vmcnt: A (first iter) and B tiles visible

    #pragma unroll
    for (int kk = 0; kk < 8; ++kk) {
      f16x8 av[4], bv[4];
      #pragma unroll
      for (int rb = 0; rb < 4; ++rb) {
        int rw = wr*64 + rb*16 + l15;
        av[rb] = *(const f16x8*)(lA + rw*512 + ((((kk<<2)|quad) ^ (l15 & 7)) << 4));
      }
      #pragma unroll
      for (int cb = 0; cb < 4; ++cb) {
        int rw = wc*64 + cb*16 + l15;
        bv[cb] = *(const f16x8*)(lB + rw*512 + ((((kk<<2)|quad) ^ (l15 & 7)) << 4));
      }
      #pragma unroll
      for (int rb = 0; rb < 4; ++rb)
        #pragma unroll
        for (int cb = 0; cb < 4; ++cb)
          acc[rb][cb] = __builtin_amdgcn_mfma_f32_16x16x32_f16(av[rb], bv[cb], acc[rb][cb], 0, 0, 0);
    }
  }
  {
    int pj0 = chbase + (NJT-1) * 128;
    if (NJT-1 == dj)
      epilogue<true >(acc, sq, y, pj0, wc, l15, i0q, sqi, yiv, sden, snum, nscale2);
    else
      epilogue<false>(acc, sq, y, pj0, wc, l15, i0q, sqi, yiv, sden, snum, nscale2);
  }

  // reduce across the 16 lanes of each quad (columns of the wave tile)
  #pragma unroll
  for (int v = 0; v < 16; ++v) {
    #pragma unroll
    for (int m = 1; m <= 8; m <<= 1) {
      sden[v] += __shfl_xor(sden[v], m);
      snum[v] += __shfl_xor(snum[v], m);
    }
  }
  if (l15 == 0) {
    int base = ((it*NCH + ch)*2 + wc) * 128;
    #pragma unroll
    for (int rb = 0; rb < 4; ++rb)
      #pragma unroll
      for (int r = 0; r < 4; ++r) {
        int rin = wr*64 + rb*16 + quad*4 + r;
        pden[base + rin] = sden[rb*4+r];
        pnum[base + rin] = snum[rb*4+r];
      }
  }
}

// ---- kernel 3: combine partials, final loss (byte-identical to R6) -------
__global__ __launch_bounds__(256) void final_kernel(
    const float* __restrict__ pden, const float* __restrict__ pnum,
    float* __restrict__ out)
{
  int tid = threadIdx.x;
  float tot = 0.f;
  for (int k = 0; k < 32; ++k) {
    int row = tid + 256*k;
    int itt = row >> 7, rin = row & 127;
    float den = 0.f, num = 0.f;
    #pragma unroll
    for (int p = 0; p < 8; ++p) {
      den += pden[(itt*8 + p)*128 + rin];
      num += pnum[(itt*8 + p)*128 + rin];
    }
    if (num > 0.f)
      tot += 0.6931471805599453f *
             (__builtin_amdgcn_logf(num) - __builtin_amdgcn_logf(den));
  }
  #pragma unroll
  for (int m = 32; m; m >>= 1) tot += __shfl_xor(tot, m);
  __shared__ float red[4];
  if ((tid & 63) == 0) red[tid >> 6] = tot;
  __syncthreads();
  if (tid == 0) out[0] = -(red[0]+red[1]+red[2]+red[3]) / 8192.0f;
}

extern "C" void kernel_launch(void* const* d_in, const int* in_sizes, int n_in,
                              void* d_out, int out_size, void* d_ws, size_t ws_size,
                              hipStream_t stream)
{
  (void)in_sizes; (void)n_in; (void)out_size; (void)ws_size;
  const float* x  = (const float*)d_in[0];
  const int* y    = (const int*)d_in[1];   // int64 in reference -> int32 here
  const float* T  = (const float*)d_in[2];
  char* ws = (char*)d_ws;
  double* gacc  = (double*)ws;                           // 16 B
  float* part_s = (float*)(ws + 1024);                   // 8 KB
  float* part_q = (float*)(ws + 1024 + 8192);            // 8 KB
  float* sq     = (float*)(ws + 32768);                  // 32 KB
  unsigned short* xh = (unsigned short*)(ws + 65536);    // 4 MB fp16
  float* pden   = (float*)(ws + 65536 + 4194304);        // 64*8*128 f32
  float* pnum   = pden + 64*8*128;

  hipLaunchKernelGGL(prep_kernel, dim3(B_ROWS/4), dim3(256), 0, stream,
                     x, xh, sq, part_s, part_q);
  hipLaunchKernelGGL(reduce_kernel, dim3(1), dim3(256), 0, stream,
                     part_s, part_q, gacc);
  hipFuncSetAttribute((const void*)snn_main,
                      hipFuncAttributeMaxDynamicSharedMemorySize, 131072);
  hipLaunchKernelGGL(snn_main, dim3(NCH, B_ROWS/128), dim3(256), 131072, stream,
                     xh, sq, y, T, gacc, pden, pnum);
  hipLaunchKernelGGL(final_kernel, dim3(1), dim3(256), 0, stream,
                     pden, pnum, (float*)d_out);
}

// Round 10
// 128.784 us; speedup vs baseline: 2.0597x; 1.1121x over previous
//
#include <hip/hip_runtime.h>

#define B_ROWS 8192
#define FEAT   256
#define NCH    4          // j-range chunks -> grid = 4 x 64 = 256 blocks
#define CH_COLS 2048
#define NJT    16         // 128-col j-tiles per chunk

typedef float f32x4 __attribute__((ext_vector_type(4)));
typedef _Float16 f16x8 __attribute__((ext_vector_type(8)));

typedef const __attribute__((address_space(1))) unsigned int* gas_ptr;
typedef __attribute__((address_space(3))) unsigned int* las_ptr;

__device__ __forceinline__ void gload_lds16(const void* g, void* l) {
  // HW semantics: LDS dest = wave-uniform base + lane*16
  __builtin_amdgcn_global_load_lds((gas_ptr)g, (las_ptr)l, 16, 0, 0);
}

// ---- kernel 1: fp16 convert, row ssq, per-block f32 partials (no atomics)
__global__ __launch_bounds__(256) void prep_kernel(
    const float* __restrict__ x, unsigned short* __restrict__ xh,
    float* __restrict__ sq, float* __restrict__ part_s,
    float* __restrict__ part_q)
{
  int tid = threadIdx.x;
  int l = tid & 63, wid = tid >> 6;
  int row = blockIdx.x * 4 + wid;
  const float4* xv = (const float4*)(x + (size_t)row * FEAT);
  float4 v = xv[l];
  ushort4 u;
  u.x = __builtin_bit_cast(unsigned short, (_Float16)v.x);
  u.y = __builtin_bit_cast(unsigned short, (_Float16)v.y);
  u.z = __builtin_bit_cast(unsigned short, (_Float16)v.z);
  u.w = __builtin_bit_cast(unsigned short, (_Float16)v.w);
  ((ushort4*)(xh + (size_t)row * FEAT))[l] = u;
  float ssq  = v.x*v.x + v.y*v.y + v.z*v.z + v.w*v.w;
  float ssum = v.x + v.y + v.z + v.w;
  #pragma unroll
  for (int m = 32; m; m >>= 1) {
    ssq  += __shfl_xor(ssq, m);
    ssum += __shfl_xor(ssum, m);
  }
  if (l == 0) sq[row] = ssq;
  __shared__ float red[8];
  if (l == 0) { red[wid*2] = ssum; red[wid*2+1] = ssq; }
  __syncthreads();
  if (tid == 0) {
    part_s[blockIdx.x] = red[0]+red[2]+red[4]+red[6];
    part_q[blockIdx.x] = red[1]+red[3]+red[5]+red[7];
  }
}

// ---- kernel 1b: reduce 2048 partials -> gacc (f64, one block)
__global__ __launch_bounds__(256) void reduce_kernel(
    const float* __restrict__ part_s, const float* __restrict__ part_q,
    double* __restrict__ gacc)
{
  int tid = threadIdx.x;
  double s = 0.0, q = 0.0;
  #pragma unroll
  for (int k = 0; k < 8; ++k) {
    s += (double)part_s[tid + 256*k];
    q += (double)part_q[tid + 256*k];
  }
  #pragma unroll
  for (int m = 32; m; m >>= 1) {
    s += __shfl_xor(s, m);
    q += __shfl_xor(q, m);
  }
  __shared__ double rs[4], rq[4];
  if ((tid & 63) == 0) { rs[tid >> 6] = s; rq[tid >> 6] = q; }
  __syncthreads();
  if (tid == 0) {
    gacc[0] = rs[0]+rs[1]+rs[2]+rs[3];
    gacc[1] = rq[0]+rq[1]+rq[2]+rq[3];
  }
}

// ---- epilogue: d2 -> dist -> exp2, accumulate den/num (wave tile 32 rows)
template<bool DIAG>
__device__ __forceinline__ void epilogue(
    const f32x4 (&acc)[2][4], const float* __restrict__ sq,
    const int* __restrict__ y, int j0, int wc, int l15,
    int i0q, const float (&sqi)[8], const int (&yiv)[8],
    float (&sden)[8], float (&snum)[8], float nscale2)
{
  int jb = j0 + wc*64 + l15;
  float sqj[4]; int yj[4];
  #pragma unroll
  for (int cb = 0; cb < 4; ++cb) {
    int j = jb + cb*16;
    sqj[cb] = sq[j];
    yj[cb]  = y[j];
  }
  #pragma unroll
  for (int rb = 0; rb < 2; ++rb) {
    #pragma unroll
    for (int r = 0; r < 4; ++r) {
      float si = sqi[rb*4+r];
      int   ig = i0q + rb*16 + r;
      int   yi = yiv[rb*4+r];
      float dacc = 0.f, nacc = 0.f;
      #pragma unroll
      for (int cb = 0; cb < 4; ++cb) {
        float S  = acc[rb][cb][r];
        float d2 = fmaf(S, -2.0f, si + sqj[cb]);
        d2 = fmaxf(d2, 0.0f);
        float e  = __builtin_amdgcn_exp2f(__builtin_amdgcn_sqrtf(d2) * nscale2);
        bool offd = !DIAG || (ig != jb + cb*16);
        dacc += offd ? e : 0.0f;
        nacc += (yi == yj[cb] && offd) ? e : 0.0f;
      }
      sden[rb*4+r] += dacc;
      snum[rb*4+r] += nacc;
    }
  }
}

// ---- kernel 2: fused GEMM + accumulation. 8 waves (512 thr) on the
// 128x128 tile -> 2 waves/SIMD. Wave tile 32(i) x 64(j).
__global__ __launch_bounds__(512, 2) void snn_main(
    const unsigned short* __restrict__ xh, const float* __restrict__ sq,
    const int* __restrict__ y, const float* __restrict__ T,
    const double* __restrict__ gacc,
    float* __restrict__ pden, float* __restrict__ pnum)
{
  extern __shared__ char smem[];
  char* lA = smem;
  char* lB = smem + 65536;
  int tid = threadIdx.x;
  int l = tid & 63, wid = tid >> 6;     // wid 0..7
  int wr = wid >> 1, wc = wid & 1;
  int quad = l >> 4, l15 = l & 15;
  int l5 = l >> 5, s31 = l & 31;
  int ch = blockIdx.x, it = blockIdx.y;
  int i0 = it * 128, chbase = ch * CH_COLS;

  const char* xbc = (const char*)xh;

  // stage A tile async (rows i0..i0+128): 64 chunks of 1024 B, 8 per wave
  {
    const char* gA = xbc + (size_t)i0 * 512;
    #pragma unroll
    for (int s = 0; s < 8; ++s) {
      int c  = wid*8 + s;
      int rw = 2*c + l5;
      int gg = s31 ^ (rw & 7);
      gload_lds16(gA + rw*512 + gg*16, lA + c*1024);
    }
  }

  // uniform scale: -10^T / std * log2(e)
  double ssum = gacc[0], sssq = gacc[1];
  const double n = (double)B_ROWS * FEAT;
  double var = (sssq - ssum * ssum / n) / (n - 1.0);
  float stdv = (float)sqrt(var);
  float p10  = __builtin_amdgcn_exp2f(T[0] * 3.3219280948873623f);
  float nscale2 = -(p10 * 1.4426950408889634f / stdv);

  int dj = -1;
  if (i0 >= chbase && i0 < chbase + CH_COLS) dj = (i0 - chbase) >> 7;

  // per-lane row stats (rows i0q + rb*16 + r)
  float sqi[8]; int yiv[8];
  int i0q = i0 + wr*32 + quad*4;
  #pragma unroll
  for (int rb = 0; rb < 2; ++rb)
    #pragma unroll
    for (int r = 0; r < 4; ++r) {
      int idx = i0q + rb*16 + r;
      sqi[rb*4+r] = sq[idx];
      yiv[rb*4+r] = y[idx];
    }

  float sden[8], snum[8];
  #pragma unroll
  for (int v = 0; v < 8; ++v) { sden[v] = 0.f; snum[v] = 0.f; }
  f32x4 acc[2][4];
  const f32x4 zero4 = {0.f, 0.f, 0.f, 0.f};

  for (int jt = 0; jt < NJT; ++jt) {
    int j0 = chbase + jt * 128;

    __syncthreads();   // all waves done reading lB of previous tile
    // issue next B tile direct-to-LDS (latency hidden by epilogue below)
    {
      const char* gB = xbc + (size_t)j0 * 512;
      #pragma unroll
      for (int s = 0; s < 8; ++s) {
        int c  = wid*8 + s;
        int rw = 2*c + l5;
        int gg = s31 ^ (rw & 7);
        gload_lds16(gB + rw*512 + gg*16, lB + c*1024);
      }
    }

    if (jt > 0) {
      int pj0 = j0 - 128;
      if (jt - 1 == dj)
        epilogue<true >(acc, sq, y, pj0, wc, l15, i0q, sqi, yiv, sden, snum, nscale2);
      else
        epilogue<false>(acc, sq, y, pj0, wc, l15, i0q, sqi, yiv, sden, snum, nscale2);
    }
    #pragma unroll
    for (int rb = 0; rb < 2; ++rb)
      #pragma unroll
      for (int cb = 0; cb < 4; ++cb)
        acc[rb][cb] = zero4;

    __syncthreads();   // drains vmcnt: A (first iter) and B tiles visible

    #pragma unroll
    for (int kk = 0; kk < 8; ++kk) {
      f16x8 av[2], bv[4];
      #pragma unroll
      for (int rb = 0; rb < 2; ++rb) {
        int rw = wr*32 + rb*16 + l15;
        av[rb] = *(const f16x8*)(lA + rw*512 + ((((kk<<2)|quad) ^ (l15 & 7)) << 4));
      }
      #pragma unroll
      for (int cb = 0; cb < 4; ++cb) {
        int rw = wc*64 + cb*16 + l15;
        bv[cb] = *(const f16x8*)(lB + rw*512 + ((((kk<<2)|quad) ^ (l15 & 7)) << 4));
      }
      #pragma unroll
      for (int rb = 0; rb < 2; ++rb)
        #pragma unroll
        for (int cb = 0; cb < 4; ++cb)
          acc[rb][cb] = __builtin_amdgcn_mfma_f32_16x16x32_f16(av[rb], bv[cb], acc[rb][cb], 0, 0, 0);
    }
  }
  {
    int pj0 = chbase + (NJT-1) * 128;
    if (NJT-1 == dj)
      epilogue<true >(acc, sq, y, pj0, wc, l15, i0q, sqi, yiv, sden, snum, nscale2);
    else
      epilogue<false>(acc, sq, y, pj0, wc, l15, i0q, sqi, yiv, sden, snum, nscale2);
  }

  // reduce across the 16 lanes of each quad (columns of the wave tile)
  #pragma unroll
  for (int v = 0; v < 8; ++v) {
    #pragma unroll
    for (int m = 1; m <= 8; m <<= 1) {
      sden[v] += __shfl_xor(sden[v], m);
      snum[v] += __shfl_xor(snum[v], m);
    }
  }
  if (l15 == 0) {
    int base = ((it*NCH + ch)*2 + wc) * 128;
    #pragma unroll
    for (int rb = 0; rb < 2; ++rb)
      #pragma unroll
      for (int r = 0; r < 4; ++r) {
        int rin = wr*32 + rb*16 + quad*4 + r;
        pden[base + rin] = sden[rb*4+r];
        pnum[base + rin] = snum[rb*4+r];
      }
  }
}

// ---- kernel 3: combine partials, final loss (32 blocks, atomic combine)
// NOTE: __builtin_amdgcn_logf is LOG2 -> must scale by ln(2). This missing
// factor was the sole cause of the R4/R5/R7/R9 failures (absmax 2.03).
__global__ __launch_bounds__(256) void final_kernel(
    const float* __restrict__ pden, const float* __restrict__ pnum,
    float* __restrict__ out)
{
  int row = blockIdx.x*256 + threadIdx.x;
  int itt = row >> 7, rin = row & 127;
  float den = 0.f, num = 0.f;
  #pragma unroll
  for (int p = 0; p < 8; ++p) {
    den += pden[(itt*8 + p)*128 + rin];
    num += pnum[(itt*8 + p)*128 + rin];
  }
  float t = (num > 0.f)
          ? 0.6931471805599453f *
            (__builtin_amdgcn_logf(num) - __builtin_amdgcn_logf(den)) : 0.f;
  #pragma unroll
  for (int m = 32; m; m >>= 1) t += __shfl_xor(t, m);
  __shared__ float red[4];
  if ((threadIdx.x & 63) == 0) red[threadIdx.x >> 6] = t;
  __syncthreads();
  if (threadIdx.x == 0)
    atomicAdd(out, -(red[0]+red[1]+red[2]+red[3]) * (1.0f/8192.0f));
}

extern "C" void kernel_launch(void* const* d_in, const int* in_sizes, int n_in,
                              void* d_out, int out_size, void* d_ws, size_t ws_size,
                              hipStream_t stream)
{
  (void)in_sizes; (void)n_in; (void)out_size; (void)ws_size;
  const float* x  = (const float*)d_in[0];
  const int* y    = (const int*)d_in[1];   // int64 in reference -> int32 here
  const float* T  = (const float*)d_in[2];
  char* ws = (char*)d_ws;
  double* gacc  = (double*)ws;                           // 16 B
  float* part_s = (float*)(ws + 1024);                   // 8 KB
  float* part_q = (float*)(ws + 1024 + 8192);            // 8 KB
  float* sq     = (float*)(ws + 32768);                  // 32 KB
  unsigned short* xh = (unsigned short*)(ws + 65536);    // 4 MB fp16
  float* pden   = (float*)(ws + 65536 + 4194304);        // 64*8*128 f32
  float* pnum   = pden + 64*8*128;

  hipMemsetAsync(d_out, 0, sizeof(float), stream);
  hipLaunchKernelGGL(prep_kernel, dim3(B_ROWS/4), dim3(256), 0, stream,
                     x, xh, sq, part_s, part_q);
  hipLaunchKernelGGL(reduce_kernel, dim3(1), dim3(256), 0, stream,
                     part_s, part_q, gacc);
  hipFuncSetAttribute((const void*)snn_main,
                      hipFuncAttributeMaxDynamicSharedMemorySize, 131072);
  hipLaunchKernelGGL(snn_main, dim3(NCH, B_ROWS/128), dim3(512), 131072, stream,
                     xh, sq, y, T, gacc, pden, pnum);
  hipLaunchKernelGGL(final_kernel, dim3(32), dim3(256), 0, stream,
                     pden, pnum, (float*)d_out);
}

// Round 11
// 120.759 us; speedup vs baseline: 2.1966x; 1.0665x over previous
//
#include <hip/hip_runtime.h>

#define B_ROWS 8192
#define FEAT   256
#define NCH    8           // j-range chunks -> grid = 8 x 64 = 512 blocks
#define CH_COLS 1024
#define NJT    16          // 64-col j-tiles per chunk

typedef float f32x4 __attribute__((ext_vector_type(4)));
typedef _Float16 f16x8 __attribute__((ext_vector_type(8)));

typedef const __attribute__((address_space(1))) unsigned int* gas_ptr;
typedef __attribute__((address_space(3))) unsigned int* las_ptr;

__device__ __forceinline__ void gload_lds16(const void* g, void* l) {
  // HW semantics: LDS dest = wave-uniform base + lane*16
  __builtin_amdgcn_global_load_lds((gas_ptr)g, (las_ptr)l, 16, 0, 0);
}

// ---- kernel 1: fp16 convert, row ssq, per-block f32 partials (R10, proven)
__global__ __launch_bounds__(256) void prep_kernel(
    const float* __restrict__ x, unsigned short* __restrict__ xh,
    float* __restrict__ sq, float* __restrict__ part_s,
    float* __restrict__ part_q)
{
  int tid = threadIdx.x;
  int l = tid & 63, wid = tid >> 6;
  int row = blockIdx.x * 4 + wid;
  const float4* xv = (const float4*)(x + (size_t)row * FEAT);
  float4 v = xv[l];
  ushort4 u;
  u.x = __builtin_bit_cast(unsigned short, (_Float16)v.x);
  u.y = __builtin_bit_cast(unsigned short, (_Float16)v.y);
  u.z = __builtin_bit_cast(unsigned short, (_Float16)v.z);
  u.w = __builtin_bit_cast(unsigned short, (_Float16)v.w);
  ((ushort4*)(xh + (size_t)row * FEAT))[l] = u;
  float ssq  = v.x*v.x + v.y*v.y + v.z*v.z + v.w*v.w;
  float ssum = v.x + v.y + v.z + v.w;
  #pragma unroll
  for (int m = 32; m; m >>= 1) {
    ssq  += __shfl_xor(ssq, m);
    ssum += __shfl_xor(ssum, m);
  }
  if (l == 0) sq[row] = ssq;
  __shared__ float red[8];
  if (l == 0) { red[wid*2] = ssum; red[wid*2+1] = ssq; }
  __syncthreads();
  if (tid == 0) {
    part_s[blockIdx.x] = red[0]+red[2]+red[4]+red[6];
    part_q[blockIdx.x] = red[1]+red[3]+red[5]+red[7];
  }
}

// ---- epilogue: wave tile 32(i) x 64(j), all waves share the 64-col j-tile
template<bool DIAG>
__device__ __forceinline__ void epilogue(
    const f32x4 (&acc)[2][4], const float* __restrict__ sq,
    const int* __restrict__ y, int j0, int l15,
    int i0q, const float (&sqi)[8], const int (&yiv)[8],
    float (&sden)[8], float (&snum)[8], float nscale2)
{
  int jb = j0 + l15;
  float sqj[4]; int yj[4];
  #pragma unroll
  for (int cb = 0; cb < 4; ++cb) {
    int j = jb + cb*16;
    sqj[cb] = sq[j];
    yj[cb]  = y[j];
  }
  #pragma unroll
  for (int rb = 0; rb < 2; ++rb) {
    #pragma unroll
    for (int r = 0; r < 4; ++r) {
      float si = sqi[rb*4+r];
      int   ig = i0q + rb*16 + r;
      int   yi = yiv[rb*4+r];
      float dacc = 0.f, nacc = 0.f;
      #pragma unroll
      for (int cb = 0; cb < 4; ++cb) {
        float S  = acc[rb][cb][r];
        float d2 = fmaf(S, -2.0f, si + sqj[cb]);
        d2 = fmaxf(d2, 0.0f);
        float e  = __builtin_amdgcn_exp2f(__builtin_amdgcn_sqrtf(d2) * nscale2);
        bool offd = !DIAG || (ig != jb + cb*16);
        dacc += offd ? e : 0.0f;
        nacc += (yi == yj[cb] && offd) ? e : 0.0f;
      }
      sden[rb*4+r] += dacc;
      snum[rb*4+r] += nacc;
    }
  }
}

// ---- kernel 2 (R7 structure, now validated): block tile 128(i) x 64(j),
// 4 waves of 32x64. A fragments register-resident (loaded once from global
// in MFMA layout -> no A-side LDS reads); LDS = 32 KB B tile only.
// launch_bounds(256,2) -> 2 co-resident blocks/CU, de-phased barriers.
__global__ __launch_bounds__(256, 2) void snn_main(
    const unsigned short* __restrict__ xh, const float* __restrict__ sq,
    const int* __restrict__ y, const float* __restrict__ T,
    const float* __restrict__ part_s, const float* __restrict__ part_q,
    float* __restrict__ pden, float* __restrict__ pnum)
{
  __shared__ __align__(16) char lB[32768];
  int tid = threadIdx.x;
  int l = tid & 63, wid = tid >> 6;     // wid = wave row strip (0..3)
  int quad = l >> 4, l15 = l & 15;
  int l5 = l >> 5, s31 = l & 31;
  int ch = blockIdx.x, it = blockIdx.y;
  int i0 = it * 128, chbase = ch * CH_COLS;
  const char* xbc = (const char*)xh;

  // A fragments -> registers: lane holds A[m = wid*32+rb*16+l15]
  // [k = kk*32 + quad*8 .. +8] = 16 B at row*512 + kk*64 + quad*16
  f16x8 areg[2][8];
  #pragma unroll
  for (int rb = 0; rb < 2; ++rb)
    #pragma unroll
    for (int kk = 0; kk < 8; ++kk)
      areg[rb][kk] = *(const f16x8*)(xbc +
          (size_t)(i0 + wid*32 + rb*16 + l15)*512 + kk*64 + quad*16);

  // scale from prep's 2048 partials (per-wave redundant; no barrier)
  float s_acc = 0.f, q_acc = 0.f;
  #pragma unroll
  for (int t = 0; t < 32; ++t) {
    s_acc += part_s[l + 64*t];
    q_acc += part_q[l + 64*t];
  }
  #pragma unroll
  for (int m = 1; m <= 32; m <<= 1) {
    s_acc += __shfl_xor(s_acc, m);
    q_acc += __shfl_xor(q_acc, m);
  }
  const double n = (double)B_ROWS * FEAT;
  double var = ((double)q_acc - (double)s_acc*(double)s_acc/n) / (n - 1.0);
  float stdv = (float)sqrt(var);
  float p10  = __builtin_amdgcn_exp2f(T[0] * 3.3219280948873623f);
  float nscale2 = -(p10 * 1.4426950408889634f / stdv);

  // per-lane row stats
  float sqi[8]; int yiv[8];
  int i0q = i0 + wid*32 + quad*4;
  #pragma unroll
  for (int rb = 0; rb < 2; ++rb)
    #pragma unroll
    for (int r = 0; r < 4; ++r) {
      int idx = i0q + rb*16 + r;
      sqi[rb*4+r] = sq[idx];
      yiv[rb*4+r] = y[idx];
    }

  float sden[8], snum[8];
  #pragma unroll
  for (int v = 0; v < 8; ++v) { sden[v] = 0.f; snum[v] = 0.f; }
  f32x4 acc[2][4];
  const f32x4 zero4 = {0.f, 0.f, 0.f, 0.f};

  for (int jt = 0; jt < NJT; ++jt) {
    int j0 = chbase + jt * 64;

    __syncthreads();   // all waves done reading lB of previous tile
    // stage next B tile (64 cols x 512 B = 32 chunks of 1024 B) to LDS
    {
      const char* gB = xbc + (size_t)j0 * 512;
      #pragma unroll
      for (int s = 0; s < 8; ++s) {
        int c  = wid*8 + s;
        int rw = 2*c + l5;
        int gg = s31 ^ (rw & 7);
        gload_lds16(gB + rw*512 + gg*16, lB + c*1024);
      }
    }

    if (jt > 0) {
      int pj0 = j0 - 64;
      if (pj0 == i0 || pj0 == i0 + 64)
        epilogue<true >(acc, sq, y, pj0, l15, i0q, sqi, yiv, sden, snum, nscale2);
      else
        epilogue<false>(acc, sq, y, pj0, l15, i0q, sqi, yiv, sden, snum, nscale2);
    }
    #pragma unroll
    for (int rb = 0; rb < 2; ++rb)
      #pragma unroll
      for (int cb = 0; cb < 4; ++cb)
        acc[rb][cb] = zero4;

    __syncthreads();   // drains vmcnt: B tile visible

    #pragma unroll
    for (int kk = 0; kk < 8; ++kk) {
      f16x8 bv[4];
      #pragma unroll
      for (int cb = 0; cb < 4; ++cb) {
        int nr = cb*16 + l15;
        bv[cb] = *(const f16x8*)(lB + nr*512 + ((((kk<<2)|quad) ^ (l15 & 7)) << 4));
      }
      #pragma unroll
      for (int rb = 0; rb < 2; ++rb)
        #pragma unroll
        for (int cb = 0; cb < 4; ++cb)
          acc[rb][cb] = __builtin_amdgcn_mfma_f32_16x16x32_f16(areg[rb][kk], bv[cb], acc[rb][cb], 0, 0, 0);
    }
  }
  {
    int pj0 = chbase + (NJT-1) * 64;
    if (pj0 == i0 || pj0 == i0 + 64)
      epilogue<true >(acc, sq, y, pj0, l15, i0q, sqi, yiv, sden, snum, nscale2);
    else
      epilogue<false>(acc, sq, y, pj0, l15, i0q, sqi, yiv, sden, snum, nscale2);
  }

  // reduce across the 16 lanes of each quad (columns), store partials
  #pragma unroll
  for (int v = 0; v < 8; ++v) {
    #pragma unroll
    for (int m = 1; m <= 8; m <<= 1) {
      sden[v] += __shfl_xor(sden[v], m);
      snum[v] += __shfl_xor(snum[v], m);
    }
  }
  if (l15 == 0) {
    int base = (it*NCH + ch) * 128;
    #pragma unroll
    for (int rb = 0; rb < 2; ++rb)
      #pragma unroll
      for (int r = 0; r < 4; ++r) {
        int rin = wid*32 + rb*16 + quad*4 + r;
        pden[base + rin] = sden[rb*4+r];
        pnum[base + rin] = snum[rb*4+r];
      }
  }
}

// ---- kernel 3: single 1024-thread block; direct write (no memset/atomic).
// __builtin_amdgcn_logf is LOG2 -> scale by ln(2)  (R4/5/7/9 bug).
__global__ __launch_bounds__(1024) void final_kernel(
    const float* __restrict__ pden, const float* __restrict__ pnum,
    float* __restrict__ out)
{
  int tid = threadIdx.x;
  float tot = 0.f;
  #pragma unroll
  for (int rr = 0; rr < 8; ++rr) {
    int row = tid + 1024*rr;
    int itt = row >> 7, rin = row & 127;
    float den = 0.f, num = 0.f;
    #pragma unroll
    for (int p = 0; p < NCH; ++p) {
      den += pden[(itt*NCH + p)*128 + rin];
      num += pnum[(itt*NCH + p)*128 + rin];
    }
    if (num > 0.f)
      tot += 0.6931471805599453f *
             (__builtin_amdgcn_logf(num) - __builtin_amdgcn_logf(den));
  }
  #pragma unroll
  for (int m = 32; m; m >>= 1) tot += __shfl_xor(tot, m);
  __shared__ float red[16];
  if ((tid & 63) == 0) red[tid >> 6] = tot;
  __syncthreads();
  if (tid == 0) {
    float s = 0.f;
    #pragma unroll
    for (int w = 0; w < 16; ++w) s += red[w];
    out[0] = -s / 8192.0f;
  }
}

extern "C" void kernel_launch(void* const* d_in, const int* in_sizes, int n_in,
                              void* d_out, int out_size, void* d_ws, size_t ws_size,
                              hipStream_t stream)
{
  (void)in_sizes; (void)n_in; (void)out_size; (void)ws_size;
  const float* x  = (const float*)d_in[0];
  const int* y    = (const int*)d_in[1];   // int64 in reference -> int32 here
  const float* T  = (const float*)d_in[2];
  char* ws = (char*)d_ws;
  float* part_s = (float*)(ws + 1024);                   // 8 KB
  float* part_q = (float*)(ws + 1024 + 8192);            // 8 KB
  float* sq     = (float*)(ws + 32768);                  // 32 KB
  unsigned short* xh = (unsigned short*)(ws + 65536);    // 4 MB fp16
  float* pden   = (float*)(ws + 65536 + 4194304);        // 64*8*128 f32
  float* pnum   = pden + 64*NCH*128;

  hipLaunchKernelGGL(prep_kernel, dim3(B_ROWS/4), dim3(256), 0, stream,
                     x, xh, sq, part_s, part_q);
  hipLaunchKernelGGL(snn_main, dim3(NCH, B_ROWS/128), dim3(256), 0, stream,
                     xh, sq, y, T, part_s, part_q, pden, pnum);
  hipLaunchKernelGGL(final_kernel, dim3(1), dim3(1024), 0, stream,
                     pden, pnum, (float*)d_out);
}